// Round 9
// baseline (3079.734 us; speedup 1.0000x reference)
//
#include <hip/hip_runtime.h>
#include <hip/hip_bf16.h>

#define B_   128
#define T_   512
#define D_   512
#define U_   1024
#define O_   512
#define K_   1536      // D + U
#define G4U_ 4096
#define NBLK 256
#define HPITCH 1032    // LDS h-row pitch in shorts (dword stride 516 ≡ 4 mod 32)
#define SENT  ((int)0x7FC07FC0)   // two bf16 NaNs; unreachable from f2b(finite gate output)

typedef __attribute__((ext_vector_type(8))) short short8;
typedef __attribute__((ext_vector_type(4))) float f32x4;
typedef __attribute__((ext_vector_type(4))) int int4v;

__device__ __align__(16) unsigned short g_xbf[(size_t)B_ * T_ * D_];   // x bf16 [b][t][d]
__device__ __align__(16) unsigned short g_Wt[(size_t)G4U_ * K_];       // W^T gate-grouped [cg][k]
__device__ __align__(16) unsigned short g_Wdt[(size_t)O_ * U_];        // Wd^T [o][u]
// h history: slot t holds h_t (slot 0 = h0). Slots 1..T sentinel-poisoned by prep.
// R9 protocol: producers volatile-store h and proceed (no drain, no flag). Consumers
// detect arrival by polling ONE dword per producer-WAVE (volatile, 4B), then fill with
// CACHED loads (L2-shared) + sentinel validate + rare volatile retry.
__device__ __align__(16) unsigned short g_hall[(size_t)(T_ + 1) * B_ * U_];

__device__ __forceinline__ unsigned short f2b(float f) {
  unsigned u = __float_as_uint(f);
  u += 0x7fffu + ((u >> 16) & 1u);   // RNE
  return (unsigned short)(u >> 16);
}

// fast activations (r6-proven: VALUBusy 18->12, absmax unchanged)
__device__ __forceinline__ float sigm_f(float x) {
  return __builtin_amdgcn_rcpf(1.f + __expf(-x));
}
__device__ __forceinline__ float tanh_f(float x) {
  return 1.f - 2.f * __builtin_amdgcn_rcpf(1.f + __expf(2.f * x));
}

__global__ void prep_kernel(const float* __restrict__ x, const float* __restrict__ h0,
                            const float* __restrict__ kern, const float* __restrict__ rkern,
                            const float* __restrict__ Wd) {
  size_t tid = (size_t)blockIdx.x * blockDim.x + threadIdx.x;
  size_t np  = (size_t)gridDim.x * blockDim.x;

  const size_t nx8 = (size_t)B_ * T_ * D_ / 8;
  const float4* xv = (const float4*)x;
  for (size_t i = tid; i < nx8; i += np) {
    float4 v0 = xv[2 * i], v1 = xv[2 * i + 1];
    unsigned short tmp[8];
    tmp[0] = f2b(v0.x); tmp[1] = f2b(v0.y); tmp[2] = f2b(v0.z); tmp[3] = f2b(v0.w);
    tmp[4] = f2b(v1.x); tmp[5] = f2b(v1.y); tmp[6] = f2b(v1.z); tmp[7] = f2b(v1.w);
    *(int4*)&g_xbf[i * 8] = *(const int4*)tmp;
  }

  // W layout (verified r1/r2): row cg = (u>>4)*64 + gate*16 + (u&15), k contiguous
  const size_t nw = (size_t)G4U_ * (K_ / 8);
  for (size_t i = tid; i < nw; i += np) {
    size_t cg = i / (K_ / 8);
    int kb = (int)(i % (K_ / 8)) * 8;
    int c = (int)(cg >> 6), g = (int)((cg >> 4) & 3), j = (int)(cg & 15);
    int n = g * 1024 + (c << 4) + j;
    unsigned short tmp[8];
#pragma unroll
    for (int q = 0; q < 8; ++q) {
      int k = kb + q;
      float v = (k < 512) ? kern[(size_t)k * G4U_ + n] : rkern[(size_t)(k - 512) * G4U_ + n];
      tmp[q] = f2b(v);
    }
    *(int4*)&g_Wt[cg * K_ + kb] = *(const int4*)tmp;
  }

  const size_t nd = (size_t)O_ * (U_ / 8);
  for (size_t i = tid; i < nd; i += np) {
    int o  = (int)(i >> 7);
    int ub = (int)(i & 127) * 8;
    unsigned short tmp[8];
#pragma unroll
    for (int q = 0; q < 8; ++q) tmp[q] = f2b(Wd[(size_t)(ub + q) * O_ + o]);
    *(int4*)&g_Wdt[(size_t)o * U_ + ub] = *(const int4*)tmp;
  }

  const size_t nh = (size_t)B_ * U_;
  for (size_t i = tid; i < nh; i += np) g_hall[i] = f2b(h0[i]);  // slot 0 = h0

  // sentinel-poison slots 1..T (re-poisoned every launch)
  {
    int4v sv; sv[0] = SENT; sv[1] = SENT; sv[2] = SENT; sv[3] = SENT;
    int4v* hs = (int4v*)&g_hall[(size_t)B_ * U_];
    const size_t ns4 = (size_t)T_ * B_ * U_ / 8;
    for (size_t i = tid; i < ns4; i += np) hs[i] = sv;
  }
}

// 256 persistent blocks x 256 threads, 1 block/CU. XCD-clustered mapping (r3-proven:
// FETCH 3.5x lower). R9 sync: flag-free NARROW data-poll.
//  - Producer: gates -> volatile dword h stores -> done (stores ARE the publication).
//  - Consumer wave: 64 lanes poll one dword per (producer, producer-wave) pair --
//    the first dword that producer-wave stores (row m0+wv*8, col u0). 4B/lane
//    volatile traffic (= old flag poll), but detect == data arrival (no drain+flag RT).
//  - Fill: CACHED 512B bursts (r5-proven, L2-shared) + sentinel validate; stragglers
//    (or stale-poisoned L2 lines) retried volatile. Common path: zero retries.
// 2 block barriers/iter (zpo, po); t=0-only extra guard. x in prefetched registers;
// x-MFMAs run pre-poll. All weights register-resident. Fast activations on the tail.
__global__ __launch_bounds__(256, 1) void lstm_kernel(const float* __restrict__ c0,
                                                      const float* __restrict__ bias,
                                                      const float* __restrict__ bd,
                                                      float* __restrict__ out) {
  const int b    = blockIdx.x;
  const int tid  = threadIdx.x;
  const int wq   = tid >> 6;
  const int lane = tid & 63;
  const int rg   = lane >> 4;
  const int fr   = lane & 15;

  // XCD-clustered logical ids
  const int xcd = b & 7, idx = b >> 3;
  const int mg  = xcd >> 1;            // row group 0..3
  const int sl  = idx * 2 + (xcd & 1); // u-tile 0..63
  const int m0  = mg * 32;
  const int ug  = sl;
  const int u0  = ug * 16;

  __shared__ __align__(16) unsigned short Ast[32 * HPITCH];   // 66 KB: staged h_t
  __shared__ f32x4 zpo[4][32][17];                            // 34 KB z partials (padded)
  __shared__ float po[4][16][20];                             // 5 KB out partials

  // ---------- one-time weight preload into registers ----------
  short8 wzx[4][4], wzh[8][4];
#pragma unroll
  for (int kt = 0; kt < 4; ++kt)
#pragma unroll
    for (int g = 0; g < 4; ++g)
      wzx[kt][g] = *(const short8*)&g_Wt[(size_t)(ug * 64 + g * 16 + fr) * K_ +
                                         wq * 128 + kt * 32 + rg * 8];
#pragma unroll
  for (int kt = 0; kt < 8; ++kt)
#pragma unroll
    for (int g = 0; g < 4; ++g)
      wzh[kt][g] = *(const short8*)&g_Wt[(size_t)(ug * 64 + g * 16 + fr) * K_ +
                                         512 + wq * 256 + kt * 32 + rg * 8];

  const int oc0 = (ug >> 1) * 16;   // out col tile
  const int orh = (ug & 1) * 16;    // out row half
  short8 wd[8];
#pragma unroll
  for (int kt = 0; kt < 8; ++kt)
    wd[kt] = *(const short8*)&g_Wdt[(size_t)(oc0 + fr) * U_ + wq * 256 + kt * 32 + rg * 8];

  // ---------- per-thread gate-element mapping ----------
  const int erow = tid >> 3;
  const int euu  = (tid & 7) * 2;
  float cv[2];
  f32x4 bv[2];
#pragma unroll
  for (int j = 0; j < 2; ++j) {
    cv[j] = c0[(size_t)(m0 + erow) * U_ + u0 + euu + j];
    f32x4 tv;
#pragma unroll
    for (int g = 0; g < 4; ++g) tv[g] = bias[g * 1024 + u0 + euu + j];
    bv[j] = tv;
  }

  const int orow = tid >> 4, ocl = tid & 15;
  const float bd_v = bd[oc0 + ocl];

  const int xcol = wq * 128 + rg * 8;   // per-wave x K-chunk column base
  // LDS A-fragment pointers (wave-private h quarter)
  const unsigned short* ahp0 = &Ast[(size_t)fr * HPITCH + wq * 256 + rg * 8];
  const unsigned short* ahp1 = ahp0 + 16 * HPITCH;
  const unsigned short* aop  = &Ast[(size_t)(orh + fr) * HPITCH + wq * 256 + rg * 8];

  // per-wave staging map: instr q covers rows {q, q+16}, 512B bursts
  const int srow = lane >> 5;          // 0 or 1 -> row offset 0 / 16
  const int sseg = lane & 31;          // 16B segment within the 512B row-slice

  // poll target: producer pp = lane>>2 (u-tile wq*16+pp), producer-wave wv = lane&3.
  // Its wave wv's first store lands at row m0+wv*8, col (wq*16+pp)*16 (dword 0).
  const size_t pofs = (size_t)(m0 + (lane & 3) * 8) * U_ + (size_t)(wq * 16 + (lane >> 2)) * 16;

  // prologue: x fragments for t=0
  short8 axf0[4], axf1[4];
  {
    const unsigned short* x0 = &g_xbf[((size_t)(m0 + fr) * T_ + 0) * D_ + xcol];
    const unsigned short* x1 = &g_xbf[((size_t)(m0 + 16 + fr) * T_ + 0) * D_ + xcol];
#pragma unroll
    for (int kt = 0; kt < 4; ++kt) {
      axf0[kt] = *(const short8*)&x0[kt * 32];
      axf1[kt] = *(const short8*)&x1[kt * 32];
    }
  }

  // Iterations 0..T_-1: x-GEMM, data-poll, cached fill+validate, h-GEMM -> h_{t+1},
  // out[t-1]. Iteration T_: poll, fill, out[T_-1] only.
  for (int t = 0; t <= T_; ++t) {
    f32x4 acc[2][4];
    if (t < T_) {
      // ---------- x-part MFMAs from registers: no dependency on h_t arrival ----------
#pragma unroll
      for (int rt = 0; rt < 2; ++rt)
#pragma unroll
        for (int g = 0; g < 4; ++g) acc[rt][g] = (f32x4){0.f, 0.f, 0.f, 0.f};
#pragma unroll
      for (int kt = 0; kt < 4; ++kt)
#pragma unroll
        for (int g = 0; g < 4; ++g) {
          acc[0][g] = __builtin_amdgcn_mfma_f32_16x16x32_bf16(axf0[kt], wzx[kt][g], acc[0][g], 0, 0, 0);
          acc[1][g] = __builtin_amdgcn_mfma_f32_16x16x32_bf16(axf1[kt], wzx[kt][g], acc[1][g], 0, 0, 0);
        }
    }

    const size_t hb = (size_t)t * (B_ * U_);

    // ---------- narrow data-poll: one dword per producer-wave (64 lanes) ----------
    if (t > 0) {
      volatile const unsigned int* dp = (volatile const unsigned int*)&g_hall[hb + pofs];
      while (*dp == (unsigned)SENT) __builtin_amdgcn_s_sleep(1);
      asm volatile("" ::: "memory");   // no fill load issues before the poll clears
    }

    // ---------- cached fill of MY 16KB quarter + sentinel validate ----------
    {
      int4v bh[16];
#pragma unroll
      for (int q = 0; q < 16; ++q)
        bh[q] = *(const int4v*)&g_hall[hb + (size_t)(m0 + q + srow * 16) * U_ +
                                      wq * 256 + sseg * 8];
      if (t > 0) {
        unsigned pend = 0u;
#pragma unroll
        for (int q = 0; q < 16; ++q) {
          int4v v = bh[q];
          if (v[0] == SENT || v[1] == SENT || v[2] == SENT || v[3] == SENT)
            pend |= (1u << q);
        }
        while (pend) {   // rare: straggler or stale-poisoned L2 line -> volatile retry
#pragma unroll
          for (int q = 0; q < 16; ++q)
            if (pend & (1u << q))
              bh[q] = *(volatile const int4v*)&g_hall[hb + (size_t)(m0 + q + srow * 16) * U_ +
                                                     wq * 256 + sseg * 8];
          unsigned np = 0u;
#pragma unroll
          for (int q = 0; q < 16; ++q)
            if (pend & (1u << q)) {
              int4v v = bh[q];
              if (v[0] == SENT || v[1] == SENT || v[2] == SENT || v[3] == SENT)
                np |= (1u << q);
            }
          pend = np;
          if (pend) __builtin_amdgcn_s_sleep(1);
        }
      }
#pragma unroll
      for (int q = 0; q < 16; ++q)
        *(int4v*)&Ast[(size_t)(q + srow * 16) * HPITCH + wq * 256 + sseg * 8] = bh[q];
    }
    // no block barrier: Ast quarter is wave-private; intra-wave ordering suffices

    if (t < T_) {
      // ---------- h-part MFMAs from my staged quarter, weights from registers ----------
#pragma unroll
      for (int kt = 0; kt < 8; ++kt) {
        short8 a0 = *(const short8*)&ahp0[kt * 32];
        short8 a1 = *(const short8*)&ahp1[kt * 32];
#pragma unroll
        for (int g = 0; g < 4; ++g) {
          acc[0][g] = __builtin_amdgcn_mfma_f32_16x16x32_bf16(a0, wzh[kt][g], acc[0][g], 0, 0, 0);
          acc[1][g] = __builtin_amdgcn_mfma_f32_16x16x32_bf16(a1, wzh[kt][g], acc[1][g], 0, 0, 0);
        }
      }

      // partials -> LDS: one f32x4 (i,f,g,o) per (row, u) element
#pragma unroll
      for (int rt = 0; rt < 2; ++rt)
#pragma unroll
        for (int r = 0; r < 4; ++r) {
          f32x4 v = {acc[rt][0][r], acc[rt][1][r], acc[rt][2][r], acc[rt][3][r]};
          zpo[wq][rt * 16 + rg * 4 + r][fr] = v;
        }
      __syncthreads();   // zpo-bar: waves converge here only

      // ---------- K-reduce + gates (fast act) + volatile packed h store ----------
      // No drain, no flag: the stores themselves are the publication.
      {
        unsigned short* hn = &g_hall[(size_t)(t + 1) * (B_ * U_)];
        float hv[2];
#pragma unroll
        for (int j = 0; j < 2; ++j) {
          f32x4 z = zpo[0][erow][euu + j] + zpo[1][erow][euu + j] +
                    zpo[2][erow][euu + j] + zpo[3][erow][euu + j];
          z += bv[j];
          float ig = sigm_f(z[0]);
          float fg = sigm_f(z[1]);
          float gg = tanh_f(z[2]);
          float og = sigm_f(z[3]);
          cv[j] = fg * cv[j] + ig * gg;
          hv[j] = og * tanh_f(cv[j]);
        }
        unsigned int pk = (unsigned)f2b(hv[0]) | ((unsigned)f2b(hv[1]) << 16);
        *(volatile unsigned int*)&hn[(size_t)(m0 + erow) * U_ + u0 + euu] = pk;
      }

      // ---------- prefetch x fragments for t+1 (off critical path) ----------
      if (t + 1 < T_) {
        const unsigned short* x0 = &g_xbf[((size_t)(m0 + fr) * T_ + (t + 1)) * D_ + xcol];
        const unsigned short* x1 = &g_xbf[((size_t)(m0 + 16 + fr) * T_ + (t + 1)) * D_ + xcol];
#pragma unroll
        for (int kt = 0; kt < 4; ++kt) {
          axf0[kt] = *(const short8*)&x0[kt * 32];
          axf1[kt] = *(const short8*)&x1[kt * 32];
        }
      }
      if (t == 0) __syncthreads();   // protect zpo reuse (no po-bar in iter 0)
    }

    // ---------- out[t-1] = h_t @ Wd + bd from my staged LDS quarter ----------
    if (t > 0) {
      f32x4 oa = {0.f, 0.f, 0.f, 0.f};
#pragma unroll
      for (int kt = 0; kt < 8; ++kt)
        oa = __builtin_amdgcn_mfma_f32_16x16x32_bf16(*(const short8*)&aop[kt * 32],
                                                     wd[kt], oa, 0, 0, 0);
#pragma unroll
      for (int r = 0; r < 4; ++r) po[wq][rg * 4 + r][fr] = oa[r];
      __syncthreads();   // po-bar
      float v = po[0][orow][ocl] + po[1][orow][ocl] + po[2][orow][ocl] +
                po[3][orow][ocl] + bd_v;
      out[((size_t)(m0 + orh + orow) * T_ + (t - 1)) * O_ + oc0 + ocl] = v;
    }
  }
}

extern "C" void kernel_launch(void* const* d_in, const int* in_sizes, int n_in,
                              void* d_out, int out_size, void* d_ws, size_t ws_size,
                              hipStream_t stream) {
  const float* x    = (const float*)d_in[0];
  const float* h0   = (const float*)d_in[1];
  const float* c0   = (const float*)d_in[2];
  const float* kern = (const float*)d_in[3];
  const float* rk   = (const float*)d_in[4];
  const float* bias = (const float*)d_in[5];
  const float* Wd   = (const float*)d_in[6];
  const float* bd   = (const float*)d_in[7];
  float* out = (float*)d_out;
  (void)in_sizes; (void)n_in; (void)d_ws; (void)ws_size; (void)out_size;

  prep_kernel<<<dim3(1024), dim3(256), 0, stream>>>(x, h0, kern, rk, Wd);
  lstm_kernel<<<dim3(NBLK), dim3(256), 0, stream>>>(c0, bias, bd, out);
}

// Round 10
// 2480.897 us; speedup vs baseline: 1.2414x; 1.2414x over previous
//
#include <hip/hip_runtime.h>
#include <hip/hip_bf16.h>

#define B_   128
#define T_   512
#define D_   512
#define U_   1024
#define O_   512
#define K_   1536      // D + U
#define G4U_ 4096
#define NBLK 256
#define HPITCH 1032    // LDS h-row pitch in shorts (dword stride 516 ≡ 4 mod 32)

typedef __attribute__((ext_vector_type(8))) short short8;
typedef __attribute__((ext_vector_type(4))) float f32x4;
typedef __attribute__((ext_vector_type(4))) int int4v;

__device__ __align__(16) unsigned short g_xbf[(size_t)B_ * T_ * D_];   // x bf16 [b][t][d]
__device__ __align__(16) unsigned short g_Wt[(size_t)G4U_ * K_];       // W^T gate-grouped [cg][k]
__device__ __align__(16) unsigned short g_Wdt[(size_t)O_ * U_];        // Wd^T [o][u]
// h history: slot t holds h_t (slot 0 = h0). Unique slot per step -> cached consumer loads.
__device__ __align__(16) unsigned short g_hall[(size_t)(T_ + 1) * B_ * U_];
__device__ unsigned int g_flag[NBLK * 32];   // per-LOGICAL-block progress, one 128B line each

__device__ __forceinline__ unsigned short f2b(float f) {
  unsigned u = __float_as_uint(f);
  u += 0x7fffu + ((u >> 16) & 1u);   // RNE
  return (unsigned short)(u >> 16);
}

// fast activations (r6-proven: VALUBusy 18->12, absmax unchanged)
__device__ __forceinline__ float sigm_f(float x) {
  return __builtin_amdgcn_rcpf(1.f + __expf(-x));
}
__device__ __forceinline__ float tanh_f(float x) {
  return 1.f - 2.f * __builtin_amdgcn_rcpf(1.f + __expf(2.f * x));
}

__global__ void prep_kernel(const float* __restrict__ x, const float* __restrict__ h0,
                            const float* __restrict__ kern, const float* __restrict__ rkern,
                            const float* __restrict__ Wd) {
  size_t tid = (size_t)blockIdx.x * blockDim.x + threadIdx.x;
  size_t np  = (size_t)gridDim.x * blockDim.x;
  if (tid < NBLK * 32) g_flag[tid] = 0u;

  const size_t nx8 = (size_t)B_ * T_ * D_ / 8;
  const float4* xv = (const float4*)x;
  for (size_t i = tid; i < nx8; i += np) {
    float4 v0 = xv[2 * i], v1 = xv[2 * i + 1];
    unsigned short tmp[8];
    tmp[0] = f2b(v0.x); tmp[1] = f2b(v0.y); tmp[2] = f2b(v0.z); tmp[3] = f2b(v0.w);
    tmp[4] = f2b(v1.x); tmp[5] = f2b(v1.y); tmp[6] = f2b(v1.z); tmp[7] = f2b(v1.w);
    *(int4*)&g_xbf[i * 8] = *(const int4*)tmp;
  }

  // W layout (verified r1/r2): row cg = (u>>4)*64 + gate*16 + (u&15), k contiguous
  const size_t nw = (size_t)G4U_ * (K_ / 8);
  for (size_t i = tid; i < nw; i += np) {
    size_t cg = i / (K_ / 8);
    int kb = (int)(i % (K_ / 8)) * 8;
    int c = (int)(cg >> 6), g = (int)((cg >> 4) & 3), j = (int)(cg & 15);
    int n = g * 1024 + (c << 4) + j;
    unsigned short tmp[8];
#pragma unroll
    for (int q = 0; q < 8; ++q) {
      int k = kb + q;
      float v = (k < 512) ? kern[(size_t)k * G4U_ + n] : rkern[(size_t)(k - 512) * G4U_ + n];
      tmp[q] = f2b(v);
    }
    *(int4*)&g_Wt[cg * K_ + kb] = *(const int4*)tmp;
  }

  const size_t nd = (size_t)O_ * (U_ / 8);
  for (size_t i = tid; i < nd; i += np) {
    int o  = (int)(i >> 7);
    int ub = (int)(i & 127) * 8;
    unsigned short tmp[8];
#pragma unroll
    for (int q = 0; q < 8; ++q) tmp[q] = f2b(Wd[(size_t)(ub + q) * O_ + o]);
    *(int4*)&g_Wdt[(size_t)o * U_ + ub] = *(const int4*)tmp;
  }

  const size_t nh = (size_t)B_ * U_;
  for (size_t i = tid; i < nh; i += np) g_hall[i] = f2b(h0[i]);  // slot 0 = h0
}

// 256 persistent blocks x 256 threads, 1 block/CU. XCD-clustered mapping (r3-proven:
// FETCH 3.5x lower). R5-proven sync: per-wave poll of own 16 producer flags, monolithic
// per-wave 16KB quarter staging (512B bursts, cached/L2-shared), no barrier in the
// wait->stage->MFMA chain. R6-proven fast activations on the producer tail.
// x path: register fragments prefetched in prior iteration; x-MFMAs pre-poll.
// All weights register-resident. 3 block barriers/iter (zpo, drain, po).
// SESSION-FINAL (r10 = r8 verbatim): the measured optimum of this design family.
// Protocol ladder: r4 5.00 / r5-r8 4.51 / r6 5.11 / r7 9.45 / r9 5.68 us/step.
// Residual is cross-CU MALL round-trip latency on the T=512 serial recurrence.
__global__ __launch_bounds__(256, 1) void lstm_kernel(const float* __restrict__ c0,
                                                      const float* __restrict__ bias,
                                                      const float* __restrict__ bd,
                                                      float* __restrict__ out) {
  const int b    = blockIdx.x;
  const int tid  = threadIdx.x;
  const int wq   = tid >> 6;
  const int lane = tid & 63;
  const int rg   = lane >> 4;
  const int fr   = lane & 15;

  // XCD-clustered logical ids
  const int xcd = b & 7, idx = b >> 3;
  const int mg  = xcd >> 1;            // row group 0..3
  const int sl  = idx * 2 + (xcd & 1); // u-tile 0..63
  const int lb  = mg * 64 + sl;        // logical id (flag index)
  const int m0  = mg * 32;
  const int ug  = sl;
  const int u0  = ug * 16;

  __shared__ __align__(16) unsigned short Ast[32 * HPITCH];   // 66 KB: staged h_t
  __shared__ f32x4 zpo[4][32][17];                            // 34 KB z partials (padded)
  __shared__ float po[4][16][20];                             // 5 KB out partials

  // ---------- one-time weight preload into registers ----------
  short8 wzx[4][4], wzh[8][4];
#pragma unroll
  for (int kt = 0; kt < 4; ++kt)
#pragma unroll
    for (int g = 0; g < 4; ++g)
      wzx[kt][g] = *(const short8*)&g_Wt[(size_t)(ug * 64 + g * 16 + fr) * K_ +
                                         wq * 128 + kt * 32 + rg * 8];
#pragma unroll
  for (int kt = 0; kt < 8; ++kt)
#pragma unroll
    for (int g = 0; g < 4; ++g)
      wzh[kt][g] = *(const short8*)&g_Wt[(size_t)(ug * 64 + g * 16 + fr) * K_ +
                                         512 + wq * 256 + kt * 32 + rg * 8];

  const int oc0 = (ug >> 1) * 16;   // out col tile
  const int orh = (ug & 1) * 16;    // out row half
  short8 wd[8];
#pragma unroll
  for (int kt = 0; kt < 8; ++kt)
    wd[kt] = *(const short8*)&g_Wdt[(size_t)(oc0 + fr) * U_ + wq * 256 + kt * 32 + rg * 8];

  // ---------- per-thread gate-element mapping ----------
  const int erow = tid >> 3;
  const int euu  = (tid & 7) * 2;
  float cv[2];
  f32x4 bv[2];
#pragma unroll
  for (int j = 0; j < 2; ++j) {
    cv[j] = c0[(size_t)(m0 + erow) * U_ + u0 + euu + j];
    f32x4 tv;
#pragma unroll
    for (int g = 0; g < 4; ++g) tv[g] = bias[g * 1024 + u0 + euu + j];
    bv[j] = tv;
  }

  const int orow = tid >> 4, ocl = tid & 15;
  const float bd_v = bd[oc0 + ocl];

  const int xcol = wq * 128 + rg * 8;   // per-wave x K-chunk column base
  // LDS A-fragment pointers (wave-private h quarter)
  const unsigned short* ahp0 = &Ast[(size_t)fr * HPITCH + wq * 256 + rg * 8];
  const unsigned short* ahp1 = ahp0 + 16 * HPITCH;
  const unsigned short* aop  = &Ast[(size_t)(orh + fr) * HPITCH + wq * 256 + rg * 8];

  // per-wave staging map: instr q covers rows {q, q+16}, 512B bursts
  const int srow = lane >> 5;          // 0 or 1 -> row offset 0 / 16
  const int sseg = lane & 31;          // 16B segment within the 512B row-slice

  // prologue: x fragments for t=0
  short8 axf0[4], axf1[4];
  {
    const unsigned short* x0 = &g_xbf[((size_t)(m0 + fr) * T_ + 0) * D_ + xcol];
    const unsigned short* x1 = &g_xbf[((size_t)(m0 + 16 + fr) * T_ + 0) * D_ + xcol];
#pragma unroll
    for (int kt = 0; kt < 4; ++kt) {
      axf0[kt] = *(const short8*)&x0[kt * 32];
      axf1[kt] = *(const short8*)&x1[kt * 32];
    }
  }

  // Iterations 0..T_-1: x-GEMM, wait own quarter, stage own quarter, h-GEMM -> h_{t+1},
  // flag, out[t-1]. Iteration T_: wait, stage, out[T_-1] only.
  for (int t = 0; t <= T_; ++t) {
    f32x4 acc[2][4];
    if (t < T_) {
      // ---------- x-part MFMAs from registers: no dependency on the flag ----------
#pragma unroll
      for (int rt = 0; rt < 2; ++rt)
#pragma unroll
        for (int g = 0; g < 4; ++g) acc[rt][g] = (f32x4){0.f, 0.f, 0.f, 0.f};
#pragma unroll
      for (int kt = 0; kt < 4; ++kt)
#pragma unroll
        for (int g = 0; g < 4; ++g) {
          acc[0][g] = __builtin_amdgcn_mfma_f32_16x16x32_bf16(axf0[kt], wzx[kt][g], acc[0][g], 0, 0, 0);
          acc[1][g] = __builtin_amdgcn_mfma_f32_16x16x32_bf16(axf1[kt], wzx[kt][g], acc[1][g], 0, 0, 0);
        }
    }

    // ---------- per-wave: wait for MY quarter's 16 producers ----------
    if (t > 0) {
      if (lane < 16) {
        unsigned int* fp = &g_flag[(mg * 64 + wq * 16 + lane) * 32];
        while (__hip_atomic_load(fp, __ATOMIC_RELAXED, __HIP_MEMORY_SCOPE_AGENT) <
               (unsigned)t)
          __builtin_amdgcn_s_sleep(1);
      }
      asm volatile("" ::: "memory");   // no slot-t load issues before the poll clears
    }

    // ---------- per-wave: stage MY 16KB quarter (rows {q,q+16}, 512B bursts) ----------
    {
      const size_t hb = (size_t)t * (B_ * U_);
      int4v bh[16];
#pragma unroll
      for (int q = 0; q < 16; ++q)
        bh[q] = *(const int4v*)&g_hall[hb + (size_t)(m0 + q + srow * 16) * U_ +
                                      wq * 256 + sseg * 8];
#pragma unroll
      for (int q = 0; q < 16; ++q)
        *(int4v*)&Ast[(size_t)(q + srow * 16) * HPITCH + wq * 256 + sseg * 8] = bh[q];
    }
    // no block barrier: Ast quarter is wave-private; intra-wave ordering suffices

    if (t < T_) {
      // ---------- h-part MFMAs from my staged quarter, weights from registers ----------
#pragma unroll
      for (int kt = 0; kt < 8; ++kt) {
        short8 a0 = *(const short8*)&ahp0[kt * 32];
        short8 a1 = *(const short8*)&ahp1[kt * 32];
#pragma unroll
        for (int g = 0; g < 4; ++g) {
          acc[0][g] = __builtin_amdgcn_mfma_f32_16x16x32_bf16(a0, wzh[kt][g], acc[0][g], 0, 0, 0);
          acc[1][g] = __builtin_amdgcn_mfma_f32_16x16x32_bf16(a1, wzh[kt][g], acc[1][g], 0, 0, 0);
        }
      }

      // partials -> LDS: one f32x4 (i,f,g,o) per (row, u) element
#pragma unroll
      for (int rt = 0; rt < 2; ++rt)
#pragma unroll
        for (int r = 0; r < 4; ++r) {
          f32x4 v = {acc[rt][0][r], acc[rt][1][r], acc[rt][2][r], acc[rt][3][r]};
          zpo[wq][rt * 16 + rg * 4 + r][fr] = v;
        }
      __syncthreads();   // zpo-bar: waves converge here only

      // ---------- K-reduce + gates (fast act) + coalesced packed h store ----------
      {
        unsigned short* hn = &g_hall[(size_t)(t + 1) * (B_ * U_)];
        float hv[2];
#pragma unroll
        for (int j = 0; j < 2; ++j) {
          f32x4 z = zpo[0][erow][euu + j] + zpo[1][erow][euu + j] +
                    zpo[2][erow][euu + j] + zpo[3][erow][euu + j];
          z += bv[j];
          float ig = sigm_f(z[0]);
          float fg = sigm_f(z[1]);
          float gg = tanh_f(z[2]);
          float og = sigm_f(z[3]);
          cv[j] = fg * cv[j] + ig * gg;
          hv[j] = og * tanh_f(cv[j]);
        }
        unsigned int pk = (unsigned)f2b(hv[0]) | ((unsigned)f2b(hv[1]) << 16);
        *(volatile unsigned int*)&hn[(size_t)(m0 + erow) * U_ + u0 + euu] = pk;
      }
      __syncthreads();   // drain-bar: all h stores at the MALL

      // ---------- publish progress ASAP ----------
      if (tid == 0)
        __hip_atomic_store(&g_flag[lb * 32], (unsigned)(t + 1), __ATOMIC_RELAXED,
                           __HIP_MEMORY_SCOPE_AGENT);

      // ---------- prefetch x fragments for t+1 (off critical path) ----------
      if (t + 1 < T_) {
        const unsigned short* x0 = &g_xbf[((size_t)(m0 + fr) * T_ + (t + 1)) * D_ + xcol];
        const unsigned short* x1 = &g_xbf[((size_t)(m0 + 16 + fr) * T_ + (t + 1)) * D_ + xcol];
#pragma unroll
        for (int kt = 0; kt < 4; ++kt) {
          axf0[kt] = *(const short8*)&x0[kt * 32];
          axf1[kt] = *(const short8*)&x1[kt * 32];
        }
      }
    }

    // ---------- out[t-1] = h_t @ Wd + bd from my staged LDS quarter ----------
    if (t > 0) {
      f32x4 oa = {0.f, 0.f, 0.f, 0.f};
#pragma unroll
      for (int kt = 0; kt < 8; ++kt)
        oa = __builtin_amdgcn_mfma_f32_16x16x32_bf16(*(const short8*)&aop[kt * 32],
                                                     wd[kt], oa, 0, 0, 0);
#pragma unroll
      for (int r = 0; r < 4; ++r) po[wq][rg * 4 + r][fr] = oa[r];
      __syncthreads();   // po-bar
      float v = po[0][orow][ocl] + po[1][orow][ocl] + po[2][orow][ocl] +
                po[3][orow][ocl] + bd_v;
      out[((size_t)(m0 + orh + orow) * T_ + (t - 1)) * O_ + oc0 + ocl] = v;
    }
  }
}

extern "C" void kernel_launch(void* const* d_in, const int* in_sizes, int n_in,
                              void* d_out, int out_size, void* d_ws, size_t ws_size,
                              hipStream_t stream) {
  const float* x    = (const float*)d_in[0];
  const float* h0   = (const float*)d_in[1];
  const float* c0   = (const float*)d_in[2];
  const float* kern = (const float*)d_in[3];
  const float* rk   = (const float*)d_in[4];
  const float* bias = (const float*)d_in[5];
  const float* Wd   = (const float*)d_in[6];
  const float* bd   = (const float*)d_in[7];
  float* out = (float*)d_out;
  (void)in_sizes; (void)n_in; (void)d_ws; (void)ws_size; (void)out_size;

  prep_kernel<<<dim3(1024), dim3(256), 0, stream>>>(x, h0, kern, rk, Wd);
  lstm_kernel<<<dim3(NBLK), dim3(256), 0, stream>>>(c0, bias, bd, out);
}